// Round 11
// baseline (165.497 us; speedup 1.0000x reference)
//
#include <hip/hip_runtime.h>
#include <math.h>

// ---------------------------------------------------------------------------
// Barrier_Net, full-f16 MFMA (16x16x32). One wave = 16 batch rows end-to-end;
// stages round-trip wave-private LDS ([row][k] f16). No __syncthreads.
// A-frag: A[m=lane&15][k=(lane>>4)*8+j]; B-frag: B[k=(lane>>4)*8+j][n=lane&15]
// C/D: col=lane&15, row=(lane>>4)*4+reg.   (HW-verified by R7/R8/R10 passing)
// R11 changes vs R10:
//  - block = 512 (8 waves) to probe the ~2-blocks/CU residency cap
//  - hard lgkmcnt(0) fences -> compiler-only reorder barriers (DS pipe is
//    in-order per wave; LDS wave-private, so RAW through LDS needs no drain)
//  - 4-deep rolling x prefetch in S1N
// ---------------------------------------------------------------------------

typedef __attribute__((ext_vector_type(8))) _Float16 f16x8;
typedef __attribute__((ext_vector_type(2))) __fp16 fp16x2;   // cvt_pkrtz's type
typedef __attribute__((ext_vector_type(4))) float f32x4;

#define XW 85   // floats per input row
#define WPB 8   // waves per block

// ---- B-frag table in d_ws: 34 frags x 64 lanes x 8 f16 (~34 KB) ----
#define FR_S1N  0    // Wp1n (K=4,  N=64) nt 0..3
#define FR_S1O  4    // Wp1o (K=2,  N=64) nt 0..3
#define FR_G2N  8    // Wp2n (K=64, N=16) kk 0..1
#define FR_G2O  10   // Wp2o
#define FR_RNA  12   // Wr1n (K=16, N=64) nt 0..3
#define FR_RNB  16   // Wr2n (K=64, N=16) kk 0..1
#define FR_ROA  18   // Wr1o
#define FR_ROB  22   // Wr2o
#define FR_PSI1 24   // Wpsi1(K=36, N=64) kk 0..1 x nt 0..3
#define FR_PSI2 32   // Wpsi2(K=64, N=2)  kk 0..1
#define N_FRAGS 34

// ---- per-wave LDS layout (bytes); strides multiple of 16 for b128 reads ----
#define BIG_STR 144   // 16 rows x (128 B data + pad)
#define PHI_STR 80    // 16 rows x (32 B data + 32 B zero + pad)
#define CAT_STR 144   // 16 rows x (72 B data + zeros to 128 + pad)
#define L_BIG 0
#define L_PHI 2304
#define L_CAT 3584
#define L_OUT 5888
#define L_BAR 6016
#define WAVE_LDS 6144   // x8 waves = 49152 B/block

__device__ __forceinline__ float fast_rcp(float x)  { return __builtin_amdgcn_rcpf(x); }
__device__ __forceinline__ float fast_sqrt(float x) { return __builtin_amdgcn_sqrtf(x); }

__device__ __forceinline__ float two_tanh(float a) {
    float ax = fabsf(a);
    float e = __expf(2.0f * ax);
    float t = 1.0f - 2.0f * fast_rcp(e + 1.0f);
    return copysignf(2.0f * t, a);
}

// Compiler-only ordering barrier: DS ops of one wave execute in issue order,
// LDS areas are wave-private, so no hardware lgkmcnt drain is needed between
// stages — only prevent the compiler from reordering across the boundary.
__device__ __forceinline__ void lds_order() {
    __asm__ __volatile__("" ::: "memory");
}

__device__ __forceinline__ unsigned pk2(float a, float b) {
    union { fp16x2 h; unsigned u; } t;
    t.h = __builtin_amdgcn_cvt_pkrtz(a, b);
    return t.u;
}
__device__ __forceinline__ f16x8 make_a4(float f0, float f1, float f2, float f3) {
    union { unsigned u[4]; f16x8 v; } U;
    U.u[0] = pk2(f0, f1); U.u[1] = pk2(f2, f3); U.u[2] = 0; U.u[3] = 0;
    return U.v;
}
__device__ __forceinline__ f16x8 make_a2(float f0, float f1) {
    union { unsigned u[4]; f16x8 v; } U;
    U.u[0] = pk2(f0, f1); U.u[1] = 0; U.u[2] = 0; U.u[3] = 0;
    return U.v;
}
__device__ __forceinline__ f16x8 lds_af(const char* area, int stride, int off, int lane) {
    int mm = lane & 15, qq = lane >> 4;
    return *(const f16x8*)(area + mm * stride + off + qq * 16);
}
__device__ __forceinline__ f16x8 load_bh(const _Float16* wsf, int frag, int lane) {
    return ((const f16x8*)(wsf + (size_t)frag * 512))[lane];
}
__device__ __forceinline__ f32x4 cinit(float b) {
    f32x4 c; c[0] = b; c[1] = b; c[2] = b; c[3] = b; return c;
}
__device__ __forceinline__ f32x4 mfma1(f16x8 a, f16x8 b, f32x4 c) {
    return __builtin_amdgcn_mfma_f32_16x16x32_f16(a, b, c, 0, 0, 0);
}

// ---------------------------------------------------------------------------
// prep: pack weights into f16 B-frag blocks, zero outside (K,N).
// ---------------------------------------------------------------------------
__global__ void bn_prep(const float* __restrict__ Wp1n, const float* __restrict__ Wp2n,
                        const float* __restrict__ Wr1n, const float* __restrict__ Wr2n,
                        const float* __restrict__ Wp1o, const float* __restrict__ Wp2o,
                        const float* __restrict__ Wr1o, const float* __restrict__ Wr2o,
                        const float* __restrict__ Wpsi1, const float* __restrict__ Wpsi2,
                        _Float16* __restrict__ wsf)
{
    int f = blockIdx.x;
    int lane = threadIdx.x;   // 64
    const float* W; int K, N, kk = 0, nt = 0, rel;
    if (f < 4)        { W = Wp1n;  K = 4;  N = 64; nt = f; }
    else if (f < 8)   { W = Wp1o;  K = 2;  N = 64; nt = f - 4; }
    else if (f < 10)  { W = Wp2n;  K = 64; N = 16; kk = f - 8; }
    else if (f < 12)  { W = Wp2o;  K = 64; N = 16; kk = f - 10; }
    else if (f < 16)  { W = Wr1n;  K = 16; N = 64; nt = f - 12; }
    else if (f < 18)  { W = Wr2n;  K = 64; N = 16; kk = f - 16; }
    else if (f < 22)  { W = Wr1o;  K = 16; N = 64; nt = f - 18; }
    else if (f < 24)  { W = Wr2o;  K = 64; N = 16; kk = f - 22; }
    else if (f < 32)  { rel = f - 24; W = Wpsi1; K = 36; N = 64; kk = rel >> 2; nt = rel & 3; }
    else              { W = Wpsi2; K = 64; N = 2;  kk = f - 32; }

    int q = lane >> 4, c = lane & 15;
    _Float16* dst = wsf + (size_t)f * 512 + lane * 8;
    for (int j = 0; j < 8; ++j) {
        int k = kk * 32 + q * 8 + j;
        int n = nt * 16 + c;
        float v = (k < K && n < N) ? W[k * N + n] : 0.f;
        dst[j] = (_Float16)v;
    }
}

// ---------------------------------------------------------------------------
// main: 1 wave = 16 rows; block 512 = 8 waves.
// ---------------------------------------------------------------------------
__global__ __launch_bounds__(512) void bn_main(
    const float* __restrict__ x, const _Float16* __restrict__ wsf,
    const float* __restrict__ bp1n, const float* __restrict__ bp2n,
    const float* __restrict__ br1n, const float* __restrict__ br2n,
    const float* __restrict__ bp1o, const float* __restrict__ bp2o,
    const float* __restrict__ br1o, const float* __restrict__ br2o,
    const float* __restrict__ bpsi1, const float* __restrict__ bpsi2,
    float* __restrict__ out, int nb)
{
    __shared__ char smem[WPB * WAVE_LDS];
    const int lane = threadIdx.x & 63;
    const int wid  = threadIdx.x >> 6;
    const int group = blockIdx.x * WPB + wid;
    const int row0 = group * 16;
    if (row0 >= nb) return;

    char* Wl   = smem + wid * WAVE_LDS;
    char* BIG  = Wl + L_BIG;
    char* PHI  = Wl + L_PHI;
    char* CAT  = Wl + L_CAT;
    char* OUTA = Wl + L_OUT;
    char* BAR  = Wl + L_BAR;

    const int m = lane & 15, q = lane >> 4, c = m;
    const bool q1b = (q & 1), q2b = (q & 2);

    // zero junk zones once: PHI bytes 32..63, CAT bytes 64..127 (per row)
    for (int i = lane; i < 128; i += 64) {
        int r = i >> 3, d = i & 7;
        *(unsigned*)(PHI + r * PHI_STR + 32 + d * 4) = 0;
    }
    for (int i = lane; i < 256; i += 64) {
        int r = i >> 4, d = i & 15;
        *(unsigned*)(CAT + r * CAT_STR + 64 + d * 4) = 0;
    }
    lds_order();

    // ---- barrier terms: lane (row=m, quad q) handles nbrs 4q..4q+3 and
    //      obstacles 2q..2q+1; 4 shuffles total ----
    {
        const float* xb = x + (size_t)(row0 + m) * XW;
        float bx = 0.f, by = 0.f;
        #pragma unroll
        for (int i = 0; i < 4; ++i) {
            int n = 4 * q + i;
            float px = -xb[5 + 4 * n], py = -xb[6 + 4 * n];
            float nrm = fast_sqrt(px * px + py * py);
            float coef = 0.05f * fast_rcp(nrm * (nrm - 0.3f));
            bx = fmaf(coef, px, bx);
            by = fmaf(coef, py, by);
        }
        #pragma unroll
        for (int i = 0; i < 2; ++i) {
            int o = 2 * q + i;
            float px = -xb[69 + 2 * o], py = -xb[70 + 2 * o];
            float nrm = fast_sqrt(px * px + py * py);
            float coef = 0.05f * fast_rcp(nrm * (nrm - 0.3f));
            bx = fmaf(coef, px, bx);
            by = fmaf(coef, py, by);
        }
        bx += __shfl_xor(bx, 16); by += __shfl_xor(by, 16);
        bx += __shfl_xor(bx, 32); by += __shfl_xor(by, 32);
        if (q == 0) { float2 bb; bb.x = bx; bb.y = by; *(float2*)(BAR + m * 8) = bb; }
    }

    // g -> CAT k=32..35 (bytes 64..71)
    if (lane < 16) {
        const float* xr = x + (size_t)(row0 + lane) * XW;
        uint2 gv;
        gv.x = pk2(xr[1], xr[2]);
        gv.y = pk2(xr[3], xr[4]);
        *(uint2*)(CAT + lane * CAT_STR + 64) = gv;
    }

    // biases (per output column c)
    float b_s1n[4], b_s1o[4], b_rna[4], b_roa[4], b_p1[4];
    #pragma unroll
    for (int nt = 0; nt < 4; ++nt) {
        b_s1n[nt] = bp1n[nt * 16 + c];
        b_s1o[nt] = bp1o[nt * 16 + c];
        b_rna[nt] = br1n[nt * 16 + c];
        b_roa[nt] = br1o[nt * 16 + c];
        b_p1[nt]  = bpsi1[nt * 16 + c];
    }
    float b_g2n = 16.f * bp2n[c];
    float b_g2o = 8.f * bp2o[c];
    float b_rnb = br2n[c];
    float b_rob = br2o[c];
    float b_p2  = (c < 2) ? bpsi2[c] : 0.f;

    // stage-ahead B-frags for S1N + G2N
    f16x8 Bs1n[4], Bg2n[2];
    #pragma unroll
    for (int nt = 0; nt < 4; ++nt) Bs1n[nt] = load_bh(wsf, FR_S1N + nt, lane);
    Bg2n[0] = load_bh(wsf, FR_G2N + 0, lane);
    Bg2n[1] = load_bh(wsf, FR_G2N + 1, lane);

    // ================= S1N: neighbor stage-1, 4-deep prefetch ===============
    // Sn[r][k] = sum_m relu(e_m . W1n[:,k] + b); M=nbr, reduce via 2 shuffles;
    // each quad stores its own nt-column block -> 64 distinct addresses.
    {
        float buf[4][4];
        #pragma unroll
        for (int i = 0; i < 4; ++i) {
            const float* xi = x + (size_t)(row0 + i) * XW + 5 + 4 * m;
            buf[i][0] = xi[0]; buf[i][1] = xi[1]; buf[i][2] = xi[2]; buf[i][3] = xi[3];
        }
        #pragma unroll 4
        for (int r = 0; r < 16; ++r) {
            int sl = r & 3;
            f16x8 A = make_a4(buf[sl][0], buf[sl][1], buf[sl][2], buf[sl][3]);
            if (r + 4 < 16) {
                const float* xn = x + (size_t)(row0 + r + 4) * XW + 5 + 4 * m;
                buf[sl][0] = xn[0]; buf[sl][1] = xn[1];
                buf[sl][2] = xn[2]; buf[sl][3] = xn[3];
            }
            float sv[4];
            #pragma unroll
            for (int nt = 0; nt < 4; ++nt) {
                f32x4 cc = mfma1(A, Bs1n[nt], cinit(b_s1n[nt]));
                float s = fmaxf(cc[0], 0.f) + fmaxf(cc[1], 0.f)
                        + fmaxf(cc[2], 0.f) + fmaxf(cc[3], 0.f);
                s += __shfl_xor(s, 16);
                s += __shfl_xor(s, 32);
                sv[nt] = s;
            }
            float w = q2b ? (q1b ? sv[3] : sv[2]) : (q1b ? sv[1] : sv[0]);
            *(_Float16*)(BIG + r * BIG_STR + (q * 16 + c) * 2) = (_Float16)w;
        }
    }
    f16x8 Brna[4];
    #pragma unroll
    for (int nt = 0; nt < 4; ++nt) Brna[nt] = load_bh(wsf, FR_RNA + nt, lane);
    lds_order();

    // ================= G2N: Sn @ Wp2n -> phi_n (PHI) ========================
    {
        f16x8 A0 = lds_af(BIG, BIG_STR, 0, lane);
        f16x8 A1 = lds_af(BIG, BIG_STR, 64, lane);
        f32x4 ca = mfma1(A0, Bg2n[0], cinit(b_g2n));
        f32x4 cb = mfma1(A1, Bg2n[1], cinit(0.f));
        #pragma unroll
        for (int reg = 0; reg < 4; ++reg)
            *(_Float16*)(PHI + (q * 4 + reg) * PHI_STR + c * 2) = (_Float16)(ca[reg] + cb[reg]);
    }
    f16x8 Brnb[2], Bs1o[4];
    Brnb[0] = load_bh(wsf, FR_RNB + 0, lane);
    Brnb[1] = load_bh(wsf, FR_RNB + 1, lane);
    #pragma unroll
    for (int nt = 0; nt < 4; ++nt) Bs1o[nt] = load_bh(wsf, FR_S1O + nt, lane);
    lds_order();

    // ================= RNA: relu(phi_n @ Wr1n + b) -> h2 (BIG) ==============
    {
        f16x8 A = lds_af(PHI, PHI_STR, 0, lane);   // k>=16 zero-filled
        #pragma unroll
        for (int nt = 0; nt < 4; ++nt) {
            f32x4 cc = mfma1(A, Brna[nt], cinit(b_rna[nt]));
            #pragma unroll
            for (int reg = 0; reg < 4; ++reg)
                *(_Float16*)(BIG + (q * 4 + reg) * BIG_STR + (nt * 16 + c) * 2) = (_Float16)fmaxf(cc[reg], 0.f);
        }
    }
    // prefetch: G2O frags + S1O x-data (used 2 stages ahead)
    f16x8 Bg2o[2];
    Bg2o[0] = load_bh(wsf, FR_G2O + 0, lane);
    Bg2o[1] = load_bh(wsf, FR_G2O + 1, lane);
    float of0[8], of1[8];
    #pragma unroll
    for (int t = 0; t < 8; ++t) {
        const float* xo = x + (size_t)(row0 + 2 * t + (m >> 3)) * XW + 69 + 2 * (m & 7);
        of0[t] = xo[0]; of1[t] = xo[1];
    }
    lds_order();

    // ================= RNB: h2 @ Wr2n + b -> rho_n (CAT k=0..15) ============
    {
        f16x8 A0 = lds_af(BIG, BIG_STR, 0, lane);
        f16x8 A1 = lds_af(BIG, BIG_STR, 64, lane);
        f32x4 ca = mfma1(A0, Brnb[0], cinit(b_rnb));
        f32x4 cb = mfma1(A1, Brnb[1], cinit(0.f));
        #pragma unroll
        for (int reg = 0; reg < 4; ++reg)
            *(_Float16*)(CAT + (q * 4 + reg) * CAT_STR + c * 2) = (_Float16)(ca[reg] + cb[reg]);
    }
    f16x8 Broa[4];
    #pragma unroll
    for (int nt = 0; nt < 4; ++nt) Broa[nt] = load_bh(wsf, FR_ROA + nt, lane);
    lds_order();

    // ================= S1O: obstacle stage-1 ================================
    {
        #pragma unroll
        for (int t = 0; t < 8; ++t) {
            f16x8 A = make_a2(of0[t], of1[t]);
            float sv[4];
            #pragma unroll
            for (int nt = 0; nt < 4; ++nt) {
                f32x4 cc = mfma1(A, Bs1o[nt], cinit(b_s1o[nt]));
                float s = fmaxf(cc[0], 0.f) + fmaxf(cc[1], 0.f)
                        + fmaxf(cc[2], 0.f) + fmaxf(cc[3], 0.f);
                s += __shfl_xor(s, 16);
                sv[nt] = s;
            }
            float w1 = q1b ? sv[1] : sv[0];
            float w2 = q1b ? sv[3] : sv[2];
            char* p = BIG + (2 * t + (q >> 1)) * BIG_STR + ((q & 1) * 16 + c) * 2;
            *(_Float16*)(p)      = (_Float16)w1;   // cols 0..31
            *(_Float16*)(p + 64) = (_Float16)w2;   // cols 32..63
        }
    }
    f16x8 Brob[2];
    Brob[0] = load_bh(wsf, FR_ROB + 0, lane);
    Brob[1] = load_bh(wsf, FR_ROB + 1, lane);
    lds_order();

    // ================= G2O -> PHI ===========================================
    {
        f16x8 A0 = lds_af(BIG, BIG_STR, 0, lane);
        f16x8 A1 = lds_af(BIG, BIG_STR, 64, lane);
        f32x4 ca = mfma1(A0, Bg2o[0], cinit(b_g2o));
        f32x4 cb = mfma1(A1, Bg2o[1], cinit(0.f));
        #pragma unroll
        for (int reg = 0; reg < 4; ++reg)
            *(_Float16*)(PHI + (q * 4 + reg) * PHI_STR + c * 2) = (_Float16)(ca[reg] + cb[reg]);
    }
    f16x8 Bp1a[4];
    #pragma unroll
    for (int nt = 0; nt < 4; ++nt) Bp1a[nt] = load_bh(wsf, FR_PSI1 + nt, lane);
    lds_order();

    // ================= ROA -> BIG ===========================================
    {
        f16x8 A = lds_af(PHI, PHI_STR, 0, lane);
        #pragma unroll
        for (int nt = 0; nt < 4; ++nt) {
            f32x4 cc = mfma1(A, Broa[nt], cinit(b_roa[nt]));
            #pragma unroll
            for (int reg = 0; reg < 4; ++reg)
                *(_Float16*)(BIG + (q * 4 + reg) * BIG_STR + (nt * 16 + c) * 2) = (_Float16)fmaxf(cc[reg], 0.f);
        }
    }
    f16x8 Bp1b[4], Bp2[2];
    #pragma unroll
    for (int nt = 0; nt < 4; ++nt) Bp1b[nt] = load_bh(wsf, FR_PSI1 + 4 + nt, lane);
    Bp2[0] = load_bh(wsf, FR_PSI2 + 0, lane);
    Bp2[1] = load_bh(wsf, FR_PSI2 + 1, lane);
    lds_order();

    // ================= ROB: h2o @ Wr2o + b -> rho_o (CAT k=16..31) ==========
    {
        f16x8 A0 = lds_af(BIG, BIG_STR, 0, lane);
        f16x8 A1 = lds_af(BIG, BIG_STR, 64, lane);
        f32x4 ca = mfma1(A0, Brob[0], cinit(b_rob));
        f32x4 cb = mfma1(A1, Brob[1], cinit(0.f));
        #pragma unroll
        for (int reg = 0; reg < 4; ++reg)
            *(_Float16*)(CAT + (q * 4 + reg) * CAT_STR + (16 + c) * 2) = (_Float16)(ca[reg] + cb[reg]);
    }
    lds_order();

    // ================= PSI1: [rho_n|rho_o|g] @ Wpsi1 -> h3 (BIG) ============
    {
        f16x8 A0 = lds_af(CAT, CAT_STR, 0, lane);    // k 0..31
        f16x8 A1 = lds_af(CAT, CAT_STR, 64, lane);   // k 32..63 (36..63 zero)
        #pragma unroll
        for (int nt = 0; nt < 4; ++nt) {
            f32x4 ca = mfma1(A0, Bp1a[nt], cinit(b_p1[nt]));
            f32x4 cb = mfma1(A1, Bp1b[nt], cinit(0.f));
            #pragma unroll
            for (int reg = 0; reg < 4; ++reg)
                *(_Float16*)(BIG + (q * 4 + reg) * BIG_STR + (nt * 16 + c) * 2) = (_Float16)fmaxf(ca[reg] + cb[reg], 0.f);
        }
    }
    lds_order();

    // ================= PSI2: h3 @ Wpsi2 -> a0,a1 ============================
    {
        f16x8 A0 = lds_af(BIG, BIG_STR, 0, lane);
        f16x8 A1 = lds_af(BIG, BIG_STR, 64, lane);
        f32x4 ca = mfma1(A0, Bp2[0], cinit(b_p2));
        f32x4 cb = mfma1(A1, Bp2[1], cinit(0.f));
        if (c < 2) {
            #pragma unroll
            for (int reg = 0; reg < 4; ++reg)
                *(float*)(OUTA + (q * 4 + reg) * 8 + c * 4) = ca[reg] + cb[reg];
        }
    }
    lds_order();

    // ================= epilogue =============================================
    if (lane < 16) {
        float2 a  = *(const float2*)(OUTA + lane * 8);
        float2 bb = *(const float2*)(BAR + lane * 8);
        float a0 = two_tanh(a.x) + bb.x;
        float a1 = two_tanh(a.y) + bb.y;
        float amax = fmaxf(fabsf(a0), fabsf(a1));
        float inv_alpha = fmaxf(amax * 0.5f, 1.0f);
        float rr = fast_rcp(inv_alpha);
        float2 o; o.x = a0 * rr; o.y = a1 * rr;
        *(float2*)(out + (size_t)(row0 + lane) * 2) = o;
    }
}

extern "C" void kernel_launch(void* const* d_in, const int* in_sizes, int n_in,
                              void* d_out, int out_size, void* d_ws, size_t ws_size,
                              hipStream_t stream) {
    const float* x     = (const float*)d_in[0];
    const float* Wp1n  = (const float*)d_in[1];
    const float* bp1n  = (const float*)d_in[2];
    const float* Wp2n  = (const float*)d_in[3];
    const float* bp2n  = (const float*)d_in[4];
    const float* Wr1n  = (const float*)d_in[5];
    const float* br1n  = (const float*)d_in[6];
    const float* Wr2n  = (const float*)d_in[7];
    const float* br2n  = (const float*)d_in[8];
    const float* Wp1o  = (const float*)d_in[9];
    const float* bp1o  = (const float*)d_in[10];
    const float* Wp2o  = (const float*)d_in[11];
    const float* bp2o  = (const float*)d_in[12];
    const float* Wr1o  = (const float*)d_in[13];
    const float* br1o  = (const float*)d_in[14];
    const float* Wr2o  = (const float*)d_in[15];
    const float* br2o  = (const float*)d_in[16];
    const float* Wpsi1 = (const float*)d_in[17];
    const float* bpsi1 = (const float*)d_in[18];
    const float* Wpsi2 = (const float*)d_in[19];
    const float* bpsi2 = (const float*)d_in[20];
    float* out = (float*)d_out;

    int nb = in_sizes[0] / XW;               // 131072
    _Float16* wsf = (_Float16*)d_ws;         // ~34 KB frag table

    bn_prep<<<N_FRAGS, 64, 0, stream>>>(Wp1n, Wp2n, Wr1n, Wr2n,
                                        Wp1o, Wp2o, Wr1o, Wr2o,
                                        Wpsi1, Wpsi2, wsf);

    int groups = (nb + 15) / 16;             // 8192
    int blocks = (groups + WPB - 1) / WPB;   // 1024
    bn_main<<<blocks, 512, 0, stream>>>(x, wsf,
                                        bp1n, bp2n, br1n, br2n,
                                        bp1o, bp2o, br1o, br2o,
                                        bpsi1, bpsi2, out, nb);
}

// Round 12
// 156.336 us; speedup vs baseline: 1.0586x; 1.0586x over previous
//
#include <hip/hip_runtime.h>
#include <math.h>

// ---------------------------------------------------------------------------
// Barrier_Net, full-f16 MFMA (16x16x32). One wave = 16 batch rows end-to-end;
// stages round-trip wave-private LDS ([row][k] f16). No __syncthreads.
// A-frag: A[m=lane&15][k=(lane>>4)*8+j]; B-frag: B[k=(lane>>4)*8+j][n=lane&15]
// C/D: col=lane&15, row=(lane>>4)*4+reg.   (HW-verified R7/R8/R10/R11 passing)
// R12 vs R10/R11:
//  - block back to 256 (R11's 512 regressed occupancy)
//  - S1N/S1O restructured: batch rows on M, iterate set elements, relu+sum
//    accumulated in registers -> ZERO shuffles (R10 had 160 ds_swizzle ops
//    each serialized behind its MFMA), all stage-1 MFMAs independent
//  - soft fences kept (R11 proved correctness: per-wave DS ordering suffices)
// ---------------------------------------------------------------------------

typedef __attribute__((ext_vector_type(8))) _Float16 f16x8;
typedef __attribute__((ext_vector_type(2))) __fp16 fp16x2;   // cvt_pkrtz's type
typedef __attribute__((ext_vector_type(4))) float f32x4;

#define XW 85   // floats per input row
#define WPB 4   // waves per block

// ---- B-frag table in d_ws: 34 frags x 64 lanes x 8 f16 (~34 KB) ----
#define FR_S1N  0    // Wp1n (K=4,  N=64) nt 0..3
#define FR_S1O  4    // Wp1o (K=2,  N=64) nt 0..3
#define FR_G2N  8    // Wp2n (K=64, N=16) kk 0..1
#define FR_G2O  10   // Wp2o
#define FR_RNA  12   // Wr1n (K=16, N=64) nt 0..3
#define FR_RNB  16   // Wr2n (K=64, N=16) kk 0..1
#define FR_ROA  18   // Wr1o
#define FR_ROB  22   // Wr2o
#define FR_PSI1 24   // Wpsi1(K=36, N=64) kk 0..1 x nt 0..3
#define FR_PSI2 32   // Wpsi2(K=64, N=2)  kk 0..1
#define N_FRAGS 34

// ---- per-wave LDS layout (bytes); strides multiple of 16 for b128 reads ----
#define BIG_STR 144   // 16 rows x (128 B data + pad)
#define PHI_STR 80    // 16 rows x (32 B data + 32 B zero + pad)
#define CAT_STR 144   // 16 rows x (72 B data + zeros to 128 + pad)
#define L_BIG 0
#define L_PHI 2304
#define L_CAT 3584
#define L_OUT 5888
#define L_BAR 6016
#define WAVE_LDS 6144   // x4 waves = 24576 B/block

__device__ __forceinline__ float fast_rcp(float x)  { return __builtin_amdgcn_rcpf(x); }
__device__ __forceinline__ float fast_sqrt(float x) { return __builtin_amdgcn_sqrtf(x); }

__device__ __forceinline__ float two_tanh(float a) {
    float ax = fabsf(a);
    float e = __expf(2.0f * ax);
    float t = 1.0f - 2.0f * fast_rcp(e + 1.0f);
    return copysignf(2.0f * t, a);
}

// Compiler-only ordering barrier (R11-proven safe: DS ops of one wave execute
// in issue order and LDS areas are wave-private).
__device__ __forceinline__ void lds_order() {
    __asm__ __volatile__("" ::: "memory");
}

__device__ __forceinline__ unsigned pk2(float a, float b) {
    union { fp16x2 h; unsigned u; } t;
    t.h = __builtin_amdgcn_cvt_pkrtz(a, b);
    return t.u;
}
__device__ __forceinline__ f16x8 make_a4(float f0, float f1, float f2, float f3) {
    union { unsigned u[4]; f16x8 v; } U;
    U.u[0] = pk2(f0, f1); U.u[1] = pk2(f2, f3); U.u[2] = 0; U.u[3] = 0;
    return U.v;
}
__device__ __forceinline__ f16x8 make_a2(float f0, float f1) {
    union { unsigned u[4]; f16x8 v; } U;
    U.u[0] = pk2(f0, f1); U.u[1] = 0; U.u[2] = 0; U.u[3] = 0;
    return U.v;
}
__device__ __forceinline__ f16x8 lds_af(const char* area, int stride, int off, int lane) {
    int mm = lane & 15, qq = lane >> 4;
    return *(const f16x8*)(area + mm * stride + off + qq * 16);
}
__device__ __forceinline__ f16x8 load_bh(const _Float16* wsf, int frag, int lane) {
    return ((const f16x8*)(wsf + (size_t)frag * 512))[lane];
}
__device__ __forceinline__ f32x4 cinit(float b) {
    f32x4 c; c[0] = b; c[1] = b; c[2] = b; c[3] = b; return c;
}
__device__ __forceinline__ f32x4 mfma1(f16x8 a, f16x8 b, f32x4 c) {
    return __builtin_amdgcn_mfma_f32_16x16x32_f16(a, b, c, 0, 0, 0);
}

// ---------------------------------------------------------------------------
// prep: pack weights into f16 B-frag blocks, zero outside (K,N).
// ---------------------------------------------------------------------------
__global__ void bn_prep(const float* __restrict__ Wp1n, const float* __restrict__ Wp2n,
                        const float* __restrict__ Wr1n, const float* __restrict__ Wr2n,
                        const float* __restrict__ Wp1o, const float* __restrict__ Wp2o,
                        const float* __restrict__ Wr1o, const float* __restrict__ Wr2o,
                        const float* __restrict__ Wpsi1, const float* __restrict__ Wpsi2,
                        _Float16* __restrict__ wsf)
{
    int f = blockIdx.x;
    int lane = threadIdx.x;   // 64
    const float* W; int K, N, kk = 0, nt = 0, rel;
    if (f < 4)        { W = Wp1n;  K = 4;  N = 64; nt = f; }
    else if (f < 8)   { W = Wp1o;  K = 2;  N = 64; nt = f - 4; }
    else if (f < 10)  { W = Wp2n;  K = 64; N = 16; kk = f - 8; }
    else if (f < 12)  { W = Wp2o;  K = 64; N = 16; kk = f - 10; }
    else if (f < 16)  { W = Wr1n;  K = 16; N = 64; nt = f - 12; }
    else if (f < 18)  { W = Wr2n;  K = 64; N = 16; kk = f - 16; }
    else if (f < 22)  { W = Wr1o;  K = 16; N = 64; nt = f - 18; }
    else if (f < 24)  { W = Wr2o;  K = 64; N = 16; kk = f - 22; }
    else if (f < 32)  { rel = f - 24; W = Wpsi1; K = 36; N = 64; kk = rel >> 2; nt = rel & 3; }
    else              { W = Wpsi2; K = 64; N = 2;  kk = f - 32; }

    int q = lane >> 4, c = lane & 15;
    _Float16* dst = wsf + (size_t)f * 512 + lane * 8;
    for (int j = 0; j < 8; ++j) {
        int k = kk * 32 + q * 8 + j;
        int n = nt * 16 + c;
        float v = (k < K && n < N) ? W[k * N + n] : 0.f;
        dst[j] = (_Float16)v;
    }
}

// ---------------------------------------------------------------------------
// main: 1 wave = 16 rows; block 256 = 4 waves.
// ---------------------------------------------------------------------------
__global__ __launch_bounds__(256) void bn_main(
    const float* __restrict__ x, const _Float16* __restrict__ wsf,
    const float* __restrict__ bp1n, const float* __restrict__ bp2n,
    const float* __restrict__ br1n, const float* __restrict__ br2n,
    const float* __restrict__ bp1o, const float* __restrict__ bp2o,
    const float* __restrict__ br1o, const float* __restrict__ br2o,
    const float* __restrict__ bpsi1, const float* __restrict__ bpsi2,
    float* __restrict__ out, int nb)
{
    __shared__ char smem[WPB * WAVE_LDS];
    const int lane = threadIdx.x & 63;
    const int wid  = threadIdx.x >> 6;
    const int group = blockIdx.x * WPB + wid;
    const int row0 = group * 16;
    if (row0 >= nb) return;

    char* Wl   = smem + wid * WAVE_LDS;
    char* BIG  = Wl + L_BIG;
    char* PHI  = Wl + L_PHI;
    char* CAT  = Wl + L_CAT;
    char* OUTA = Wl + L_OUT;
    char* BAR  = Wl + L_BAR;

    const int m = lane & 15, q = lane >> 4, c = m;
    const float* xrow = x + (size_t)(row0 + m) * XW;   // this lane's batch row

    // zero junk zones once: PHI bytes 32..63, CAT bytes 64..127 (per row)
    for (int i = lane; i < 128; i += 64) {
        int r = i >> 3, d = i & 7;
        *(unsigned*)(PHI + r * PHI_STR + 32 + d * 4) = 0;
    }
    for (int i = lane; i < 256; i += 64) {
        int r = i >> 4, d = i & 15;
        *(unsigned*)(CAT + r * CAT_STR + 64 + d * 4) = 0;
    }
    lds_order();

    // ---- barrier terms: lane (row=m, quad q) handles nbrs 4q..4q+3 and
    //      obstacles 2q..2q+1; 4 shuffles total ----
    {
        float bx = 0.f, by = 0.f;
        #pragma unroll
        for (int i = 0; i < 4; ++i) {
            int n = 4 * q + i;
            float px = -xrow[5 + 4 * n], py = -xrow[6 + 4 * n];
            float nrm = fast_sqrt(px * px + py * py);
            float coef = 0.05f * fast_rcp(nrm * (nrm - 0.3f));
            bx = fmaf(coef, px, bx);
            by = fmaf(coef, py, by);
        }
        #pragma unroll
        for (int i = 0; i < 2; ++i) {
            int o = 2 * q + i;
            float px = -xrow[69 + 2 * o], py = -xrow[70 + 2 * o];
            float nrm = fast_sqrt(px * px + py * py);
            float coef = 0.05f * fast_rcp(nrm * (nrm - 0.3f));
            bx = fmaf(coef, px, bx);
            by = fmaf(coef, py, by);
        }
        bx += __shfl_xor(bx, 16); by += __shfl_xor(by, 16);
        bx += __shfl_xor(bx, 32); by += __shfl_xor(by, 32);
        if (q == 0) { float2 bb; bb.x = bx; bb.y = by; *(float2*)(BAR + m * 8) = bb; }
    }

    // g -> CAT k=32..35 (bytes 64..71)
    if (lane < 16) {
        const float* xr = x + (size_t)(row0 + lane) * XW;
        uint2 gv;
        gv.x = pk2(xr[1], xr[2]);
        gv.y = pk2(xr[3], xr[4]);
        *(uint2*)(CAT + lane * CAT_STR + 64) = gv;
    }

    // biases (per output column c)
    float b_s1n[4], b_s1o[4], b_rna[4], b_roa[4], b_p1[4];
    #pragma unroll
    for (int nt = 0; nt < 4; ++nt) {
        b_s1n[nt] = bp1n[nt * 16 + c];
        b_s1o[nt] = bp1o[nt * 16 + c];
        b_rna[nt] = br1n[nt * 16 + c];
        b_roa[nt] = br1o[nt * 16 + c];
        b_p1[nt]  = bpsi1[nt * 16 + c];
    }
    float b_g2n = 16.f * bp2n[c];
    float b_g2o = 8.f * bp2o[c];
    float b_rnb = br2n[c];
    float b_rob = br2o[c];
    float b_p2  = (c < 2) ? bpsi2[c] : 0.f;

    // stage-ahead B-frags for S1N + G2N
    f16x8 Bs1n[4], Bg2n[2];
    #pragma unroll
    for (int nt = 0; nt < 4; ++nt) Bs1n[nt] = load_bh(wsf, FR_S1N + nt, lane);
    Bg2n[0] = load_bh(wsf, FR_G2N + 0, lane);
    Bg2n[1] = load_bh(wsf, FR_G2N + 1, lane);

    // ================= S1N: rows-on-M, iterate neighbors, NO shuffles =======
    // C[r][n] = e[r, mm] . W1n[:, n] + b   (one MFMA per (mm, nt))
    // Sn[r][n] = sum_mm relu(C) accumulated in registers (C-layout), then one
    // f16 store per (nt, reg) -> 64 distinct addresses per store op.
    {
        f32x4 acc[4];
        #pragma unroll
        for (int nt = 0; nt < 4; ++nt) acc[nt] = cinit(0.f);
        float p0 = xrow[5], p1 = xrow[6], p2 = xrow[7], p3 = xrow[8];
        #pragma unroll 4
        for (int mm = 0; mm < 16; ++mm) {
            float n0, n1, n2, n3;
            if (mm + 1 < 16) {
                const float* xn = xrow + 5 + 4 * (mm + 1);
                n0 = xn[0]; n1 = xn[1]; n2 = xn[2]; n3 = xn[3];
            }
            f16x8 A = make_a4(p0, p1, p2, p3);
            #pragma unroll
            for (int nt = 0; nt < 4; ++nt) {
                f32x4 cc = mfma1(A, Bs1n[nt], cinit(b_s1n[nt]));
                #pragma unroll
                for (int reg = 0; reg < 4; ++reg)
                    acc[nt][reg] += fmaxf(cc[reg], 0.f);
            }
            if (mm + 1 < 16) { p0 = n0; p1 = n1; p2 = n2; p3 = n3; }
        }
        #pragma unroll
        for (int nt = 0; nt < 4; ++nt)
            #pragma unroll
            for (int reg = 0; reg < 4; ++reg)
                *(_Float16*)(BIG + (q * 4 + reg) * BIG_STR + (nt * 16 + c) * 2)
                    = (_Float16)acc[nt][reg];
    }
    f16x8 Brna[4];
    #pragma unroll
    for (int nt = 0; nt < 4; ++nt) Brna[nt] = load_bh(wsf, FR_RNA + nt, lane);
    lds_order();

    // ================= G2N: Sn @ Wp2n -> phi_n (PHI) ========================
    {
        f16x8 A0 = lds_af(BIG, BIG_STR, 0, lane);
        f16x8 A1 = lds_af(BIG, BIG_STR, 64, lane);
        f32x4 ca = mfma1(A0, Bg2n[0], cinit(b_g2n));
        f32x4 cb = mfma1(A1, Bg2n[1], cinit(0.f));
        #pragma unroll
        for (int reg = 0; reg < 4; ++reg)
            *(_Float16*)(PHI + (q * 4 + reg) * PHI_STR + c * 2) = (_Float16)(ca[reg] + cb[reg]);
    }
    f16x8 Brnb[2], Bs1o[4];
    Brnb[0] = load_bh(wsf, FR_RNB + 0, lane);
    Brnb[1] = load_bh(wsf, FR_RNB + 1, lane);
    #pragma unroll
    for (int nt = 0; nt < 4; ++nt) Bs1o[nt] = load_bh(wsf, FR_S1O + nt, lane);
    lds_order();

    // ================= RNA: relu(phi_n @ Wr1n + b) -> h2 (BIG) ==============
    {
        f16x8 A = lds_af(PHI, PHI_STR, 0, lane);   // k>=16 zero-filled
        #pragma unroll
        for (int nt = 0; nt < 4; ++nt) {
            f32x4 cc = mfma1(A, Brna[nt], cinit(b_rna[nt]));
            #pragma unroll
            for (int reg = 0; reg < 4; ++reg)
                *(_Float16*)(BIG + (q * 4 + reg) * BIG_STR + (nt * 16 + c) * 2) = (_Float16)fmaxf(cc[reg], 0.f);
        }
    }
    f16x8 Bg2o[2];
    Bg2o[0] = load_bh(wsf, FR_G2O + 0, lane);
    Bg2o[1] = load_bh(wsf, FR_G2O + 1, lane);
    lds_order();

    // ================= RNB: h2 @ Wr2n + b -> rho_n (CAT k=0..15) ============
    {
        f16x8 A0 = lds_af(BIG, BIG_STR, 0, lane);
        f16x8 A1 = lds_af(BIG, BIG_STR, 64, lane);
        f32x4 ca = mfma1(A0, Brnb[0], cinit(b_rnb));
        f32x4 cb = mfma1(A1, Brnb[1], cinit(0.f));
        #pragma unroll
        for (int reg = 0; reg < 4; ++reg)
            *(_Float16*)(CAT + (q * 4 + reg) * CAT_STR + c * 2) = (_Float16)(ca[reg] + cb[reg]);
    }
    f16x8 Broa[4];
    #pragma unroll
    for (int nt = 0; nt < 4; ++nt) Broa[nt] = load_bh(wsf, FR_ROA + nt, lane);
    lds_order();

    // ================= S1O: rows-on-M, iterate obstacles, NO shuffles =======
    {
        f32x4 acc[4];
        #pragma unroll
        for (int nt = 0; nt < 4; ++nt) acc[nt] = cinit(0.f);
        #pragma unroll
        for (int oo = 0; oo < 8; ++oo) {
            f16x8 A = make_a2(xrow[69 + 2 * oo], xrow[70 + 2 * oo]);
            #pragma unroll
            for (int nt = 0; nt < 4; ++nt) {
                f32x4 cc = mfma1(A, Bs1o[nt], cinit(b_s1o[nt]));
                #pragma unroll
                for (int reg = 0; reg < 4; ++reg)
                    acc[nt][reg] += fmaxf(cc[reg], 0.f);
            }
        }
        #pragma unroll
        for (int nt = 0; nt < 4; ++nt)
            #pragma unroll
            for (int reg = 0; reg < 4; ++reg)
                *(_Float16*)(BIG + (q * 4 + reg) * BIG_STR + (nt * 16 + c) * 2)
                    = (_Float16)acc[nt][reg];
    }
    f16x8 Brob[2];
    Brob[0] = load_bh(wsf, FR_ROB + 0, lane);
    Brob[1] = load_bh(wsf, FR_ROB + 1, lane);
    lds_order();

    // ================= G2O -> PHI ===========================================
    {
        f16x8 A0 = lds_af(BIG, BIG_STR, 0, lane);
        f16x8 A1 = lds_af(BIG, BIG_STR, 64, lane);
        f32x4 ca = mfma1(A0, Bg2o[0], cinit(b_g2o));
        f32x4 cb = mfma1(A1, Bg2o[1], cinit(0.f));
        #pragma unroll
        for (int reg = 0; reg < 4; ++reg)
            *(_Float16*)(PHI + (q * 4 + reg) * PHI_STR + c * 2) = (_Float16)(ca[reg] + cb[reg]);
    }
    f16x8 Bp1a[4];
    #pragma unroll
    for (int nt = 0; nt < 4; ++nt) Bp1a[nt] = load_bh(wsf, FR_PSI1 + nt, lane);
    lds_order();

    // ================= ROA -> BIG ===========================================
    {
        f16x8 A = lds_af(PHI, PHI_STR, 0, lane);
        #pragma unroll
        for (int nt = 0; nt < 4; ++nt) {
            f32x4 cc = mfma1(A, Broa[nt], cinit(b_roa[nt]));
            #pragma unroll
            for (int reg = 0; reg < 4; ++reg)
                *(_Float16*)(BIG + (q * 4 + reg) * BIG_STR + (nt * 16 + c) * 2) = (_Float16)fmaxf(cc[reg], 0.f);
        }
    }
    f16x8 Bp1b[4], Bp2[2];
    #pragma unroll
    for (int nt = 0; nt < 4; ++nt) Bp1b[nt] = load_bh(wsf, FR_PSI1 + 4 + nt, lane);
    Bp2[0] = load_bh(wsf, FR_PSI2 + 0, lane);
    Bp2[1] = load_bh(wsf, FR_PSI2 + 1, lane);
    lds_order();

    // ================= ROB: h2o @ Wr2o + b -> rho_o (CAT k=16..31) ==========
    {
        f16x8 A0 = lds_af(BIG, BIG_STR, 0, lane);
        f16x8 A1 = lds_af(BIG, BIG_STR, 64, lane);
        f32x4 ca = mfma1(A0, Brob[0], cinit(b_rob));
        f32x4 cb = mfma1(A1, Brob[1], cinit(0.f));
        #pragma unroll
        for (int reg = 0; reg < 4; ++reg)
            *(_Float16*)(CAT + (q * 4 + reg) * CAT_STR + (16 + c) * 2) = (_Float16)(ca[reg] + cb[reg]);
    }
    lds_order();

    // ================= PSI1: [rho_n|rho_o|g] @ Wpsi1 -> h3 (BIG) ============
    {
        f16x8 A0 = lds_af(CAT, CAT_STR, 0, lane);    // k 0..31
        f16x8 A1 = lds_af(CAT, CAT_STR, 64, lane);   // k 32..63 (36..63 zero)
        #pragma unroll
        for (int nt = 0; nt < 4; ++nt) {
            f32x4 ca = mfma1(A0, Bp1a[nt], cinit(b_p1[nt]));
            f32x4 cb = mfma1(A1, Bp1b[nt], cinit(0.f));
            #pragma unroll
            for (int reg = 0; reg < 4; ++reg)
                *(_Float16*)(BIG + (q * 4 + reg) * BIG_STR + (nt * 16 + c) * 2) = (_Float16)fmaxf(ca[reg] + cb[reg], 0.f);
        }
    }
    lds_order();

    // ================= PSI2: h3 @ Wpsi2 -> a0,a1 ============================
    {
        f16x8 A0 = lds_af(BIG, BIG_STR, 0, lane);
        f16x8 A1 = lds_af(BIG, BIG_STR, 64, lane);
        f32x4 ca = mfma1(A0, Bp2[0], cinit(b_p2));
        f32x4 cb = mfma1(A1, Bp2[1], cinit(0.f));
        if (c < 2) {
            #pragma unroll
            for (int reg = 0; reg < 4; ++reg)
                *(float*)(OUTA + (q * 4 + reg) * 8 + c * 4) = ca[reg] + cb[reg];
        }
    }
    lds_order();

    // ================= epilogue =============================================
    if (lane < 16) {
        float2 a  = *(const float2*)(OUTA + lane * 8);
        float2 bb = *(const float2*)(BAR + lane * 8);
        float a0 = two_tanh(a.x) + bb.x;
        float a1 = two_tanh(a.y) + bb.y;
        float amax = fmaxf(fabsf(a0), fabsf(a1));
        float inv_alpha = fmaxf(amax * 0.5f, 1.0f);
        float rr = fast_rcp(inv_alpha);
        float2 o; o.x = a0 * rr; o.y = a1 * rr;
        *(float2*)(out + (size_t)(row0 + lane) * 2) = o;
    }
}

extern "C" void kernel_launch(void* const* d_in, const int* in_sizes, int n_in,
                              void* d_out, int out_size, void* d_ws, size_t ws_size,
                              hipStream_t stream) {
    const float* x     = (const float*)d_in[0];
    const float* Wp1n  = (const float*)d_in[1];
    const float* bp1n  = (const float*)d_in[2];
    const float* Wp2n  = (const float*)d_in[3];
    const float* bp2n  = (const float*)d_in[4];
    const float* Wr1n  = (const float*)d_in[5];
    const float* br1n  = (const float*)d_in[6];
    const float* Wr2n  = (const float*)d_in[7];
    const float* br2n  = (const float*)d_in[8];
    const float* Wp1o  = (const float*)d_in[9];
    const float* bp1o  = (const float*)d_in[10];
    const float* Wp2o  = (const float*)d_in[11];
    const float* bp2o  = (const float*)d_in[12];
    const float* Wr1o  = (const float*)d_in[13];
    const float* br1o  = (const float*)d_in[14];
    const float* Wr2o  = (const float*)d_in[15];
    const float* br2o  = (const float*)d_in[16];
    const float* Wpsi1 = (const float*)d_in[17];
    const float* bpsi1 = (const float*)d_in[18];
    const float* Wpsi2 = (const float*)d_in[19];
    const float* bpsi2 = (const float*)d_in[20];
    float* out = (float*)d_out;

    int nb = in_sizes[0] / XW;               // 131072
    _Float16* wsf = (_Float16*)d_ws;         // ~34 KB frag table

    bn_prep<<<N_FRAGS, 64, 0, stream>>>(Wp1n, Wp2n, Wr1n, Wr2n,
                                        Wp1o, Wp2o, Wr1o, Wr2o,
                                        Wpsi1, Wpsi2, wsf);

    int groups = (nb + 15) / 16;             // 8192
    int blocks = (groups + WPB - 1) / WPB;   // 2048
    bn_main<<<blocks, 256, 0, stream>>>(x, wsf,
                                        bp1n, bp2n, br1n, br2n,
                                        bp1o, bp2o, br1o, br2o,
                                        bpsi1, bpsi2, out, nb);
}